// Round 3
// baseline (272.541 us; speedup 1.0000x reference)
//
#include <hip/hip_runtime.h>

#define BATCH 2048
#define VOCAB 256
#define KDIM 16384
#define BM 128               // 4 waves x 32 rows each
#define BK 32
#define KCHUNK 512
#define NT (KCHUNK / BK)     // 16 K-steps per chunk
#define NKCH (KDIM / KCHUNK) // 32 K-chunks (grid.y)
#define LN10 2.302585092994046f

typedef __attribute__((ext_vector_type(8))) short short8;
typedef __attribute__((ext_vector_type(4))) float f32x4;

#define FENCE asm volatile("" ::: "memory")

__device__ __forceinline__ unsigned short f2bf_rne(float f) {
  unsigned int u = __float_as_uint(f);
  u += 0x7fffu + ((u >> 16) & 1u);
  return (unsigned short)(u >> 16);
}
// binary values are exactly 0.0f/1.0f -> truncation is exact
__device__ __forceinline__ unsigned int pack2(float lo, float hi) {
  return (__float_as_uint(lo) >> 16) | (__float_as_uint(hi) & 0xffff0000u);
}

__device__ __forceinline__ void async16(void* lds, const void* g) {
  __builtin_amdgcn_global_load_lds(
      (const __attribute__((address_space(1))) unsigned int*)g,
      (__attribute__((address_space(3))) unsigned int*)lds, 16, 0, 0);
}

// ---------------- log_w precompute: logw = bf16(log(10*sigmoid(raw))) -------
__global__ __launch_bounds__(256) void k_logw(const float* __restrict__ raw,
                                              unsigned short* __restrict__ logw) {
  int i = blockIdx.x * 256 + threadIdx.x; // float4 index, exact grid
  float4 x = ((const float4*)raw)[i];
  ushort4 r;
  r.x = f2bf_rne(LN10 - log1pf(expf(-x.x)));
  r.y = f2bf_rne(LN10 - log1pf(expf(-x.y)));
  r.z = f2bf_rne(LN10 - log1pf(expf(-x.z)));
  r.w = f2bf_rne(LN10 - log1pf(expf(-x.w)));
  ((ushort4*)logw)[i] = r;
}

// ---------------- main K-split MFMA GEMM ------------------------------------
// grid (16, 32) = 512 blocks = 2/CU. 256 threads (4 waves).
// A: global->reg direct (per-wave-private rows, no LDS).
// B: LDS dbuf 2 x 16 KB, global_load_lds linear dest + pre-swizzled source.
//    B tile [256 rows][64 B]; 16-B slot swizzle: phys_slot = slot ^ ((row>>1)&3)
// Pipeline: raw s_barrier pairs + counted vmcnt(8) (T3/T4) - never drain to 0
// in the main loop. Per iter exactly 8 vmem ops: 4 global_load_lds (B) +
// 4 global_load_dwordx4 (A).
__global__ __launch_bounds__(256) void k_gemm(
    const float* __restrict__ binary, const unsigned short* __restrict__ logw,
    float* __restrict__ accb, float* __restrict__ nact) {
  __shared__ char Bsm0[16384];
  __shared__ char Bsm1[16384];

  const int tid = threadIdx.x;
  const int wv = tid >> 6;
  const int lane = tid & 63;
  const int l15 = lane & 15;
  const int lhi = lane >> 4;
  const int m0 = blockIdx.x * BM;
  const int k0 = blockIdx.y * KCHUNK;

  // B staging source (pre-swizzled): instr i covers rows wv*64+i*16..+16
  const int brow = lane >> 2;                      // row within 16-row group
  const int bks = (lane & 3) ^ ((lane >> 3) & 3);  // swizzled k-slot
  const unsigned short* bsrc =
      logw + (size_t)(wv * 64 + brow) * KDIM + k0 + bks * 8;

  // A sources: frag rows = m0 + wv*32 + {0,16} + l15, k = k0 + t*32 + lhi*8
  const float* asrc0 = binary + (size_t)(m0 + wv * 32 + l15) * KDIM + k0 + lhi * 8;
  const float* asrc1 = asrc0 + (size_t)16 * KDIM;

  // B read: logical (row = n*16 + l15, slot = lhi) -> phys slot swizzled
  const int rdoff = l15 * 64 + ((lhi ^ ((l15 >> 1) & 3)) << 4);

  f32x4 acc[2][16];
#pragma unroll
  for (int m = 0; m < 2; ++m)
#pragma unroll
    for (int n = 0; n < 16; ++n) acc[m][n] = f32x4{0.f, 0.f, 0.f, 0.f};
  float s0 = 0.f, s1 = 0.f;
  float4 Ae[4], Ao[4]; // even/odd A reg sets: {f0lo,f0hi,f1lo,f1hi}

  auto B_STAGE = [&](int t, char* B) {
#pragma unroll
    for (int i = 0; i < 4; ++i)
      async16(B + (wv * 4 + i) * 1024, bsrc + (size_t)i * 16 * KDIM + t * BK);
  };
  auto A_LOAD = [&](int t, float4* A) {
    const float4* p0 = (const float4*)(asrc0 + t * BK);
    const float4* p1 = (const float4*)(asrc1 + t * BK);
    A[0] = p0[0]; A[1] = p0[1]; A[2] = p1[0]; A[3] = p1[1];
  };
  auto COMPUTE = [&](const float4* A, const char* B) {
    s0 += A[0].x + A[0].y + A[0].z + A[0].w + A[1].x + A[1].y + A[1].z + A[1].w;
    s1 += A[2].x + A[2].y + A[2].z + A[2].w + A[3].x + A[3].y + A[3].z + A[3].w;
    union { short8 s; unsigned int u[4]; } a0, a1;
    a0.u[0] = pack2(A[0].x, A[0].y); a0.u[1] = pack2(A[0].z, A[0].w);
    a0.u[2] = pack2(A[1].x, A[1].y); a0.u[3] = pack2(A[1].z, A[1].w);
    a1.u[0] = pack2(A[2].x, A[2].y); a1.u[1] = pack2(A[2].z, A[2].w);
    a1.u[2] = pack2(A[3].x, A[3].y); a1.u[3] = pack2(A[3].z, A[3].w);
#pragma unroll
    for (int n = 0; n < 16; ++n) {
      short8 b = *(const short8*)(B + n * 1024 + rdoff);
      acc[0][n] = __builtin_amdgcn_mfma_f32_16x16x32_bf16(a0.s, b, acc[0][n], 0, 0, 0);
      acc[1][n] = __builtin_amdgcn_mfma_f32_16x16x32_bf16(a1.s, b, acc[1][n], 0, 0, 0);
    }
  };

  // prologue: issue tile 0 (B then A), never waited here
  B_STAGE(0, Bsm0);
  FENCE;
  A_LOAD(0, Ae);
  FENCE;

#pragma unroll 1
  for (int t = 0; t < NT; t += 2) {
    // ---- even step: compute (Ae, Bsm0), prefetch t+1 into (Ao, Bsm1) ----
    FENCE;
    __builtin_amdgcn_s_barrier(); // prev compute done reading Bsm1
    FENCE;
    B_STAGE(t + 1, Bsm1);
    FENCE;
    A_LOAD(t + 1, Ao);
    FENCE;
    asm volatile("s_waitcnt vmcnt(8)" ::: "memory"); // tile t landed; t+1 in flight
    __builtin_amdgcn_s_barrier(); // all waves' B(t) staged
    FENCE;
    COMPUTE(Ae, Bsm0);
    // ---- odd step: compute (Ao, Bsm1), prefetch t+2 into (Ae, Bsm0) ----
    FENCE;
    __builtin_amdgcn_s_barrier();
    FENCE;
    if (t + 2 < NT) {
      B_STAGE(t + 2, Bsm0);
      FENCE;
      A_LOAD(t + 2, Ae);
      FENCE;
      asm volatile("s_waitcnt vmcnt(8)" ::: "memory");
    } else {
      asm volatile("s_waitcnt vmcnt(0)" ::: "memory"); // drain tail
    }
    __builtin_amdgcn_s_barrier();
    FENCE;
    COMPUTE(Ao, Bsm1);
  }

  // n_active partials: lanes {l, l^16, l^32, l^48} share a row (per m-frag)
  float t0 = s0, t1 = s1;
  t0 += __shfl_xor(t0, 16, 64); t0 += __shfl_xor(t0, 32, 64);
  t1 += __shfl_xor(t1, 16, 64); t1 += __shfl_xor(t1, 32, 64);
  if (lane < 16) {
    atomicAdd(&nact[m0 + wv * 32 + l15], t0);
    atomicAdd(&nact[m0 + wv * 32 + 16 + l15], t1);
  }

  // K-split reduction: fp32 atomics. C/D layout: col=lane&15, row=lhi*4+i
#pragma unroll
  for (int m = 0; m < 2; ++m)
#pragma unroll
    for (int n = 0; n < 16; ++n)
#pragma unroll
      for (int i = 0; i < 4; ++i) {
        int r = m0 + wv * 32 + m * 16 + lhi * 4 + i;
        int c = n * 16 + l15;
        atomicAdd(&accb[(size_t)r * VOCAB + c], acc[m][n][i]);
      }
}

// ---------------- epilogue: logits = exp(log_sum / max(n_active,1)) ---------
__global__ __launch_bounds__(256) void k_out(float* __restrict__ io,
                                             const float* __restrict__ nact) {
  int b = blockIdx.x;
  int v = threadIdx.x;
  float n = fmaxf(nact[b], 1.0f);
  size_t idx = (size_t)b * VOCAB + v;
  io[idx] = expf(io[idx] / n);
}

extern "C" void kernel_launch(void* const* d_in, const int* in_sizes, int n_in,
                              void* d_out, int out_size, void* d_ws, size_t ws_size,
                              hipStream_t stream) {
  const float* binary = (const float*)d_in[0];
  const float* raw = (const float*)d_in[1];
  float* out = (float*)d_out;
  char* ws = (char*)d_ws;
  unsigned short* logw = (unsigned short*)ws;             // 8 MB
  float* nact = (float*)(ws + (size_t)8 * 1024 * 1024);   // 8 KB

  hipMemsetAsync(out, 0, (size_t)BATCH * VOCAB * sizeof(float), stream);
  hipMemsetAsync(nact, 0, BATCH * sizeof(float), stream);

  k_logw<<<(VOCAB * KDIM / 4) / 256, 256, 0, stream>>>(raw, logw);

  dim3 g(BATCH / BM, NKCH);
  k_gemm<<<g, 256, 0, stream>>>(binary, logw, out, nact);

  k_out<<<BATCH, VOCAB, 0, stream>>>(out, nact);
}

// Round 4
// 240.345 us; speedup vs baseline: 1.1340x; 1.1340x over previous
//
#include <hip/hip_runtime.h>

#define BATCH 2048
#define VOCAB 256
#define KDIM 16384
#define BM 64
#define BK 32
#define S_SPLIT 8
#define KCHUNK (KDIM / S_SPLIT)  // 2048
#define NT (KCHUNK / BK)         // 64 K-steps per block
#define LN10 2.302585092994046f

typedef __attribute__((ext_vector_type(8))) short short8;
typedef __attribute__((ext_vector_type(4))) float f32x4;

#define FENCE asm volatile("" ::: "memory")

__device__ __forceinline__ unsigned short f2bf_rne(float f) {
  unsigned int u = __float_as_uint(f);
  u += 0x7fffu + ((u >> 16) & 1u);
  return (unsigned short)(u >> 16);
}
// binary values are exactly 0.0f/1.0f -> truncation is exact
__device__ __forceinline__ unsigned int pack2(float lo, float hi) {
  return (__float_as_uint(lo) >> 16) | (__float_as_uint(hi) & 0xffff0000u);
}

__device__ __forceinline__ void async16(void* lds, const void* g) {
  __builtin_amdgcn_global_load_lds(
      (const __attribute__((address_space(1))) unsigned int*)g,
      (__attribute__((address_space(3))) unsigned int*)lds, 16, 0, 0);
}

// ---------------- log_w precompute: logw = bf16(log(10*sigmoid(raw))) -------
__global__ __launch_bounds__(256) void k_logw(const float* __restrict__ raw,
                                              unsigned short* __restrict__ logw) {
  int i = blockIdx.x * 256 + threadIdx.x; // float4 index, exact grid
  float4 x = ((const float4*)raw)[i];
  ushort4 r;
  r.x = f2bf_rne(LN10 - log1pf(expf(-x.x)));
  r.y = f2bf_rne(LN10 - log1pf(expf(-x.y)));
  r.z = f2bf_rne(LN10 - log1pf(expf(-x.z)));
  r.w = f2bf_rne(LN10 - log1pf(expf(-x.w)));
  ((ushort4*)logw)[i] = r;
}

// ---------------- main K-split MFMA GEMM ------------------------------------
// grid (32, 8) = 256 blocks = 1/CU. 4 waves x 16 rows, full N=256 per wave.
// A: global->reg (2 dwordx4/lane/tile). B: LDS ring-4 x 16KB (64KB static),
// global_load_lds linear dest + pre-swizzled source, 4-slot swizzle on 64B rows.
// K-rotation: tile t reads k-window ((t+phase)&63)*BK -> spreads HBM channels.
// Depth-3 prefetch: 6 vmem ops/tile, steady-state s_waitcnt vmcnt(18).
// PART=1: unique-writer fp32 partials (no atomics). PART=0: atomicAdd fallback.
template <int PART>
__global__ __launch_bounds__(256) void k_gemm(
    const float* __restrict__ binary, const unsigned short* __restrict__ logw,
    float* __restrict__ outp, float* __restrict__ nactp) {
  __shared__ char smem[65536];
  char* const Bb0 = smem;
  char* const Bb1 = smem + 16384;
  char* const Bb2 = smem + 32768;
  char* const Bb3 = smem + 49152;

  const int tid = threadIdx.x;
  const int wv = tid >> 6;
  const int lane = tid & 63;
  const int l15 = lane & 15;
  const int lhi = lane >> 4;
  const int bx = blockIdx.x;
  const int by = blockIdx.y;
  const int phase = ((bx & 7) + by * 8) & (NT - 1);

  // A source: row = bx*64 + wv*16 + l15, col base = by*KCHUNK + lhi*8
  const float* asrc =
      binary + (size_t)(bx * BM + wv * 16 + l15) * KDIM + by * KCHUNK + lhi * 8;

  // B staging source (pre-swizzled): instr i covers rows wv*64+i*16+(lane>>2)
  const int brow = lane >> 2;
  const int bslot = (lane & 3) ^ (brow & 3);
  const unsigned short* bsrc =
      logw + (size_t)(wv * 64 + brow) * KDIM + by * KCHUNK + bslot * 8;
  // B staging LDS dest: wave-uniform base + lane*16 (linear)
  const int bdst = wv * 4096 + lane * 16;

  // B read: logical (row = n*16 + l15, slot = lhi), phys slot = slot^(row&3)
  const int rdoff = l15 * 64 + ((lhi ^ (l15 & 3)) << 4);

  f32x4 acc[16];
#pragma unroll
  for (int n = 0; n < 16; ++n) acc[n] = f32x4{0.f, 0.f, 0.f, 0.f};
  float asum = 0.f;
  float4 A0[2], A1[2], A2[2], A3[2];

  auto STAGE = [&](int t, char* B, float4* A) {
    const int kk = ((t + phase) & (NT - 1)) * BK;
#pragma unroll
    for (int i = 0; i < 4; ++i)
      async16(B + bdst + i * 1024, bsrc + (size_t)i * 16 * KDIM + kk);
    const float4* p = (const float4*)(asrc + kk);
    A[0] = p[0];
    A[1] = p[1];
  };
  auto COMPUTE = [&](const char* B, const float4* A) {
    asum += A[0].x + A[0].y + A[0].z + A[0].w +
            A[1].x + A[1].y + A[1].z + A[1].w;
    union { short8 s; unsigned int u[4]; } af;
    af.u[0] = pack2(A[0].x, A[0].y);
    af.u[1] = pack2(A[0].z, A[0].w);
    af.u[2] = pack2(A[1].x, A[1].y);
    af.u[3] = pack2(A[1].z, A[1].w);
#pragma unroll
    for (int n = 0; n < 16; ++n) {
      short8 bf = *(const short8*)(B + n * 1024 + rdoff);
      // swapped operands: D row-index = vocab, col-index = batch (lane&15)
      acc[n] = __builtin_amdgcn_mfma_f32_16x16x32_bf16(bf, af.s, acc[n], 0, 0, 0);
    }
  };

#define BAR __builtin_amdgcn_s_barrier()
#define VMW(N) asm volatile("s_waitcnt vmcnt(" #N ")" ::: "memory")

  // prologue: tiles 0,1,2 in flight (18 vmem ops)
  STAGE(0, Bb0, A0); FENCE;
  STAGE(1, Bb1, A1); FENCE;
  STAGE(2, Bb2, A2); FENCE;

#pragma unroll 1
  for (int t = 0; t < NT - 4; t += 4) {
    BAR; FENCE; STAGE(t + 3, Bb3, A3); FENCE; VMW(18); BAR; FENCE;
    COMPUTE(Bb0, A0); FENCE;
    BAR; FENCE; STAGE(t + 4, Bb0, A0); FENCE; VMW(18); BAR; FENCE;
    COMPUTE(Bb1, A1); FENCE;
    BAR; FENCE; STAGE(t + 5, Bb1, A1); FENCE; VMW(18); BAR; FENCE;
    COMPUTE(Bb2, A2); FENCE;
    BAR; FENCE; STAGE(t + 6, Bb2, A2); FENCE; VMW(18); BAR; FENCE;
    COMPUTE(Bb3, A3); FENCE;
  }
  // tail: tiles 60..63 (tile 63 staged at first sub-step)
  BAR; FENCE; STAGE(NT - 1, Bb3, A3); FENCE; VMW(18); BAR; FENCE;
  COMPUTE(Bb0, A0); FENCE;
  BAR; FENCE; VMW(12); BAR; FENCE;
  COMPUTE(Bb1, A1); FENCE;
  BAR; FENCE; VMW(6); BAR; FENCE;
  COMPUTE(Bb2, A2); FENCE;
  BAR; FENCE; VMW(0); BAR; FENCE;
  COMPUTE(Bb3, A3); FENCE;

  // n_active row partial: lanes {l,l^16,l^32,l^48} cover row l15's 4 k-phases
  float s = asum;
  s += __shfl_xor(s, 16, 64);
  s += __shfl_xor(s, 32, 64);
  const int row = bx * BM + wv * 16 + l15;

  if (PART) {
    if (lane < 16) nactp[by * BATCH + row] = s;
    float* dst = outp + ((size_t)by * BATCH + row) * VOCAB + lhi * 4;
#pragma unroll
    for (int n = 0; n < 16; ++n)
      *(float4*)(dst + n * 16) =
          (float4){acc[n][0], acc[n][1], acc[n][2], acc[n][3]};
  } else {
    if (lane < 16) atomicAdd(&nactp[row], s);
#pragma unroll
    for (int n = 0; n < 16; ++n)
#pragma unroll
      for (int i = 0; i < 4; ++i)
        atomicAdd(&outp[(size_t)row * VOCAB + n * 16 + lhi * 4 + i], acc[n][i]);
  }
}

// ---------------- reduce (partial path): sum splits, divide, exp ------------
__global__ __launch_bounds__(256) void k_reduce(const float* __restrict__ part,
                                                const float* __restrict__ nactp,
                                                float* __restrict__ out) {
  int b = blockIdx.x;
  int v = threadIdx.x;
  float sum = 0.f, n = 0.f;
#pragma unroll
  for (int i = 0; i < S_SPLIT; ++i) {
    sum += part[((size_t)i * BATCH + b) * VOCAB + v];
    n += nactp[i * BATCH + b];
  }
  out[(size_t)b * VOCAB + v] = expf(sum / fmaxf(n, 1.f));
}

// ---------------- epilogue (atomic path) ------------------------------------
__global__ __launch_bounds__(256) void k_out(float* __restrict__ io,
                                             const float* __restrict__ nact) {
  int b = blockIdx.x;
  int v = threadIdx.x;
  float n = fmaxf(nact[b], 1.0f);
  size_t idx = (size_t)b * VOCAB + v;
  io[idx] = expf(io[idx] / n);
}

extern "C" void kernel_launch(void* const* d_in, const int* in_sizes, int n_in,
                              void* d_out, int out_size, void* d_ws, size_t ws_size,
                              hipStream_t stream) {
  const float* binary = (const float*)d_in[0];
  const float* raw = (const float*)d_in[1];
  float* out = (float*)d_out;
  char* ws = (char*)d_ws;

  const size_t LOGW_B = (size_t)VOCAB * KDIM * 2;          // 8 MB
  const size_t NACT_B = (size_t)S_SPLIT * BATCH * 4;       // 64 KB
  const size_t PART_B = (size_t)S_SPLIT * BATCH * VOCAB * 4; // 16 MB
  unsigned short* logw = (unsigned short*)ws;
  float* nactp = (float*)(ws + LOGW_B);
  float* part = (float*)(ws + LOGW_B + NACT_B);

  k_logw<<<(VOCAB * KDIM / 4) / 256, 256, 0, stream>>>(raw, logw);

  dim3 g(BATCH / BM, S_SPLIT);
  if (ws_size >= LOGW_B + NACT_B + PART_B) {
    // atomic-free path: unique-writer partials + reduce
    k_gemm<1><<<g, 256, 0, stream>>>(binary, logw, part, nactp);
    k_reduce<<<BATCH, VOCAB, 0, stream>>>(part, nactp, out);
  } else {
    // fallback: accumulate with atomics directly into out
    hipMemsetAsync(out, 0, (size_t)BATCH * VOCAB * sizeof(float), stream);
    hipMemsetAsync(nactp, 0, BATCH * sizeof(float), stream);
    k_gemm<0><<<g, 256, 0, stream>>>(binary, logw, out, nactp);
    k_out<<<BATCH, VOCAB, 0, stream>>>(out, nactp);
  }
}